// Round 2
// baseline (310.966 us; speedup 1.0000x reference)
//
#include <hip/hip_runtime.h>
#include <stdint.h>

typedef _Float16 f16;
typedef f16 half8 __attribute__((ext_vector_type(8)));
typedef f16 half4 __attribute__((ext_vector_type(4)));
typedef float floatx4 __attribute__((ext_vector_type(4)));

#define MFMA_F16(A, B, Cc) __builtin_amdgcn_mfma_f32_16x16x32_f16((A), (B), (Cc), 0, 0, 0)

// Problem constants: B=4, H=W=64 -> N=4096, C=256, d=32
static constexpr int NB  = 4;
static constexpr int NN  = 4096;
static constexpr int NC  = 256;
static constexpr int ND  = 32;
static constexpr int PIX = NB * NN;  // 16384

// Device-global scratch (avoids any ws_size assumptions). Fully rewritten every launch.
__device__ f16 g_WbT[320 * 256];              // [j][k]; j<32: wq col, 32..63: wk col, 64..319: wv col
__device__ f16 g_Qh[(size_t)PIX * ND];        // [b*N+n][32] f16
__device__ f16 g_Kh[(size_t)PIX * ND];        // [b*N+n][32] f16
__device__ f16 g_VbT[(size_t)NB * NC * NN];   // [b][c][n]  f16 (V transposed)

// ---------------------------------------------------------------------------
// Kernel 1: weights fp32 -> f16, transposed so K-dim is contiguous.
__global__ __launch_bounds__(256) void prep_weights(const float* __restrict__ wq,
                                                    const float* __restrict__ wk,
                                                    const float* __restrict__ wv) {
  const int tid = blockIdx.x * 256 + threadIdx.x;
  if (tid >= 320 * 256) return;
  const int j = tid >> 8;    // output column 0..319
  const int k = tid & 255;   // input channel
  float v;
  if (j < 32)      v = wq[k * 32 + j];
  else if (j < 64) v = wk[k * 32 + (j - 32)];
  else             v = wv[k * 256 + (j - 64)];
  g_WbT[j * 256 + k] = (f16)v;
}

// ---------------------------------------------------------------------------
// Kernel 2: QKV projection. [16384,256] x [256,320] via 16x16x32 f16 MFMA.
// Block = 256 thr (4 waves x 16 rows), M-tile = 64 rows, full N=320 per block.
// V output is transposed through LDS into g_VbT[b][c][n].
__global__ __launch_bounds__(256) void proj_qkv(const float* __restrict__ x,
                                                const float* __restrict__ bq,
                                                const float* __restrict__ bk,
                                                const float* __restrict__ bv) {
  __shared__ f16 xs[64 * 32];    // [row][k]   4 KB
  __shared__ f16 wsT[320 * 32];  // [j][k]    20 KB
  __shared__ f16 vt[256 * 64];   // [c][row]  32 KB (epilogue transpose)

  const int tid  = threadIdx.x;
  const int lane = tid & 63;
  const int wid  = tid >> 6;   // wave 0..3
  const int qd   = lane >> 4;  // quad 0..3
  const int c16  = lane & 15;
  const int p0   = blockIdx.x * 64;
  const floatx4 zero4 = {0.f, 0.f, 0.f, 0.f};

  floatx4 acc[20];
#pragma unroll
  for (int i = 0; i < 20; ++i) acc[i] = zero4;

  for (int kk = 0; kk < 256; kk += 32) {
    // stage x tile [64][32] as f16 (each thread: 8 floats -> 8 halfs)
    {
      const int r = tid >> 2, g = tid & 3;
      const floatx4* s4 = (const floatx4*)(x + (size_t)(p0 + r) * NC + kk + g * 8);
      const floatx4 xa = s4[0], xb = s4[1];
      half8 h;
      h[0] = (f16)xa[0]; h[1] = (f16)xa[1]; h[2] = (f16)xa[2]; h[3] = (f16)xa[3];
      h[4] = (f16)xb[0]; h[5] = (f16)xb[1]; h[6] = (f16)xb[2]; h[7] = (f16)xb[3];
      *(half8*)&xs[r * 32 + g * 8] = h;
    }
    // stage W^T tile [320][32]
#pragma unroll
    for (int i = 0; i < 10; ++i) {
      const int cid = tid + 256 * i;  // 2560 chunks of 4 halfs
      const int j = cid >> 3, m = cid & 7;
      *(half4*)&wsT[j * 32 + m * 4] = *(const half4*)&g_WbT[j * 256 + kk + m * 4];
    }
    __syncthreads();
    const half8 a = *(const half8*)&xs[(wid * 16 + c16) * 32 + qd * 8];
#pragma unroll
    for (int nt = 0; nt < 20; ++nt) {
      const half8 bfr = *(const half8*)&wsT[(nt * 16 + c16) * 32 + qd * 8];
      acc[nt] = MFMA_F16(a, bfr, acc[nt]);
    }
    __syncthreads();
  }

  // epilogue: C/D layout row=qd*4+r (local), col=c16 (+16*nt)
#pragma unroll
  for (int nt = 0; nt < 20; ++nt) {
    const int j = nt * 16 + c16;
    const float bias = (j < 32) ? bq[j] : (j < 64) ? bk[j - 32] : bv[j - 64];
#pragma unroll
    for (int r = 0; r < 4; ++r) {
      const int rl = wid * 16 + qd * 4 + r;  // row within 64-row tile
      const int p  = p0 + rl;                // global pixel
      const float val = acc[nt][r] + bias;
      if (j < 32) {
        g_Qh[(size_t)p * ND + j] = (f16)val;
      } else if (j < 64) {
        g_Kh[(size_t)p * ND + (j - 32)] = (f16)val;
      } else {
        vt[(j - 64) * 64 + rl] = (f16)val;
      }
    }
  }
  __syncthreads();
  // coalesced store of the transposed V tile
  const int b  = p0 >> 12;
  const int n0 = p0 & (NN - 1);
#pragma unroll
  for (int i = 0; i < 16; ++i) {
    const int cid = tid + 256 * i;  // 4096 chunks of 4 halfs
    const int c = cid >> 4, m = cid & 15;
    *(half4*)(g_VbT + ((size_t)(b * NC + c)) * NN + n0 + m * 4) =
        *(const half4*)&vt[c * 64 + m * 4];
  }
}

// ---------------------------------------------------------------------------
// Kernel 3: flash attention. Block = 64 q-rows (4 waves x 16), keys streamed
// in 32-key tiles. S^T = K*Q^T so softmax row-reduce is shfl_xor(16/32) only.
// P goes C-layout -> A-layout via a 1KB/wave LDS round-trip (m120 transform).
__global__ __launch_bounds__(256) void attn_kernel(const float* __restrict__ x,
                                                   float* __restrict__ out) {
  __shared__ f16 ks[32 * 32];      // [key][feat]  2 KB
  __shared__ f16 vsT[256 * 32];    // [c][key]    16 KB
  __shared__ f16 ps[4 * 16 * 32];  // [wave][q][key] 4 KB

  const int tid  = threadIdx.x;
  const int lane = tid & 63;
  const int wid  = tid >> 6;
  const int qd   = lane >> 4;
  const int c16  = lane & 15;
  const int b    = blockIdx.y;
  const int q0   = blockIdx.x * 64 + wid * 16;  // wave's q window
  const floatx4 zero4 = {0.f, 0.f, 0.f, 0.f};

  // Q as MFMA B-operand: lane holds Q[q = c16][feat = qd*8..+7]
  const half8 qf = *(const half8*)(g_Qh + ((size_t)(b * NN + q0 + c16)) * ND + qd * 8);

  floatx4 acc[16];  // O accumulator: rows q=qd*4+r, cols c=nt*16+c16
#pragma unroll
  for (int i = 0; i < 16; ++i) acc[i] = zero4;
  float m_i = -1e30f, l_i = 0.f;

  for (int k0 = 0; k0 < NN; k0 += 32) {
    // ---- stage K tile (2 KB, contiguous) ----
    if (tid < 128) {
      *(half8*)&ks[tid * 8] = *(const half8*)(g_Kh + ((size_t)(b * NN + k0)) * ND + tid * 8);
    }
    // ---- stage V^T tile (16 KB): vsT[c][key] from g_VbT[b][c][k0..k0+32) ----
#pragma unroll
    for (int i = 0; i < 4; ++i) {
      const int v = tid + 256 * i;  // 1024 chunks of 8 halfs
      const int c = v >> 2, part = v & 3;
      *(half8*)&vsT[c * 32 + part * 8] =
          *(const half8*)(g_VbT + ((size_t)(b * NC + c)) * NN + k0 + part * 8);
    }
    __syncthreads();

    // ---- S^T = K_tile * Q^T : two 16x16x32 MFMAs ----
    const half8 a0 = *(const half8*)&ks[c16 * 32 + qd * 8];
    const half8 a1 = *(const half8*)&ks[(16 + c16) * 32 + qd * 8];
    floatx4 st0 = MFMA_F16(a0, qf, zero4);  // keys k0+qd*4+r, q=c16
    floatx4 st1 = MFMA_F16(a1, qf, zero4);  // keys k0+16+qd*4+r

    // ---- online softmax (row q = c16, replicated across the 4 quads) ----
    float tm = fmaxf(fmaxf(fmaxf(st0[0], st0[1]), fmaxf(st0[2], st0[3])),
                     fmaxf(fmaxf(st1[0], st1[1]), fmaxf(st1[2], st1[3])));
    tm = fmaxf(tm, __shfl_xor(tm, 16));
    tm = fmaxf(tm, __shfl_xor(tm, 32));
    const float m_new = fmaxf(m_i, tm);
    const float alpha = __expf(m_i - m_new);

    float p0v[4], p1v[4];
    float ts = 0.f;
#pragma unroll
    for (int r = 0; r < 4; ++r) { p0v[r] = __expf(st0[r] - m_new); ts += p0v[r]; }
#pragma unroll
    for (int r = 0; r < 4; ++r) { p1v[r] = __expf(st1[r] - m_new); ts += p1v[r]; }
    ts += __shfl_xor(ts, 16);
    ts += __shfl_xor(ts, 32);
    l_i = alpha * l_i + ts;
    m_i = m_new;

    // ---- P (C-layout) -> LDS -> A-layout ----
    half4 h0, h1;
#pragma unroll
    for (int r = 0; r < 4; ++r) { h0[r] = (f16)p0v[r]; h1[r] = (f16)p1v[r]; }
    *(half4*)&ps[wid * 512 + c16 * 32 + qd * 4] = h0;        // keys local qd*4..+3
    *(half4*)&ps[wid * 512 + c16 * 32 + 16 + qd * 4] = h1;   // keys local 16+qd*4..+3

    // ---- O rescale (skipped once the running max stabilizes) ----
    if (__any(alpha < 1.0f)) {
      float a4[4];
#pragma unroll
      for (int r = 0; r < 4; ++r) a4[r] = __shfl(alpha, qd * 4 + r);
#pragma unroll
      for (int nt = 0; nt < 16; ++nt) {
#pragma unroll
        for (int r = 0; r < 4; ++r) acc[nt][r] *= a4[r];
      }
    }

    // ---- PV: O += P * V (16 MFMAs over the 256 channels) ----
    const half8 pa = *(const half8*)&ps[wid * 512 + c16 * 32 + qd * 8];
#pragma unroll
    for (int nt = 0; nt < 16; ++nt) {
      const half8 bfr = *(const half8*)&vsT[(nt * 16 + c16) * 32 + qd * 8];
      acc[nt] = MFMA_F16(pa, bfr, acc[nt]);
    }
    __syncthreads();
  }

  // ---- epilogue: normalize by l, add residual, store fp32 ----
  float linv[4];
#pragma unroll
  for (int r = 0; r < 4; ++r) linv[r] = 1.0f / __shfl(l_i, qd * 4 + r);
#pragma unroll
  for (int nt = 0; nt < 16; ++nt) {
#pragma unroll
    for (int r = 0; r < 4; ++r) {
      const int qrow = q0 + qd * 4 + r;
      const int c = nt * 16 + c16;
      const size_t idx = ((size_t)(b * NN + qrow)) * NC + c;
      out[idx] = acc[nt][r] * linv[r] + x[idx];
    }
  }
}

// ---------------------------------------------------------------------------
extern "C" void kernel_launch(void* const* d_in, const int* in_sizes, int n_in,
                              void* d_out, int out_size, void* d_ws, size_t ws_size,
                              hipStream_t stream) {
  (void)in_sizes; (void)n_in; (void)d_ws; (void)ws_size; (void)out_size;
  const float* x  = (const float*)d_in[0];
  const float* wq = (const float*)d_in[1];
  const float* bq = (const float*)d_in[2];
  const float* wk = (const float*)d_in[3];
  const float* bk = (const float*)d_in[4];
  const float* wv = (const float*)d_in[5];
  const float* bv = (const float*)d_in[6];
  float* out = (float*)d_out;

  hipLaunchKernelGGL(prep_weights, dim3(320), dim3(256), 0, stream, wq, wk, wv);
  hipLaunchKernelGGL(proj_qkv, dim3(256), dim3(256), 0, stream, x, bq, bk, bv);
  hipLaunchKernelGGL(attn_kernel, dim3(64, 4), dim3(256), 0, stream, x, out);
}

// Round 3
// 232.012 us; speedup vs baseline: 1.3403x; 1.3403x over previous
//
#include <hip/hip_runtime.h>
#include <stdint.h>

typedef _Float16 f16;
typedef f16 half8 __attribute__((ext_vector_type(8)));
typedef f16 half4 __attribute__((ext_vector_type(4)));
typedef float floatx4 __attribute__((ext_vector_type(4)));

#define MFMA_F16(A, B, Cc) __builtin_amdgcn_mfma_f32_16x16x32_f16((A), (B), (Cc), 0, 0, 0)

// Problem constants: B=4, H=W=64 -> N=4096, C=256, d=32
static constexpr int NB  = 4;
static constexpr int NN  = 4096;
static constexpr int NC  = 256;
static constexpr int ND  = 32;
static constexpr int PIX = NB * NN;  // 16384
static constexpr int NS  = 4;        // key splits (flash split-K for occupancy)
static constexpr int KS  = NN / NS;  // 1024 keys per split

// LDS row strides padded 32 -> 36 halfs: dword stride 18 spreads the 16 c16
// lanes over 16 distinct banks (32-half rows put them on 2 banks -> 8-way).
static constexpr int PAD = 36;

// Device-global scratch. Fully rewritten every launch.
__device__ f16 g_WbT[320 * 256];              // [j][k]
__device__ f16 g_Qh[(size_t)PIX * ND];        // [b*N+n][32]
__device__ f16 g_Kh[(size_t)PIX * ND];        // [b*N+n][32]
__device__ f16 g_VbT[(size_t)NB * NC * NN];   // [b][c][n]
__device__ f16 g_Of[(size_t)NS * PIX * NC];   // per-split normalized O (f16)
__device__ float g_m[NS * PIX];               // per-split running max
__device__ float g_l[NS * PIX];               // per-split denom

// ---------------------------------------------------------------------------
__global__ __launch_bounds__(256) void prep_weights(const float* __restrict__ wq,
                                                    const float* __restrict__ wk,
                                                    const float* __restrict__ wv) {
  const int tid = blockIdx.x * 256 + threadIdx.x;
  if (tid >= 320 * 256) return;
  const int j = tid >> 8;
  const int k = tid & 255;
  float v;
  if (j < 32)      v = wq[k * 32 + j];
  else if (j < 64) v = wk[k * 32 + (j - 32)];
  else             v = wv[k * 256 + (j - 64)];
  g_WbT[j * 256 + k] = (f16)v;
}

// ---------------------------------------------------------------------------
// QKV projection (unchanged from round 2 — passed; revisit after attn).
__global__ __launch_bounds__(256) void proj_qkv(const float* __restrict__ x,
                                                const float* __restrict__ bq,
                                                const float* __restrict__ bk,
                                                const float* __restrict__ bv) {
  __shared__ f16 xs[64 * 32];
  __shared__ f16 wsT[320 * 32];
  __shared__ f16 vt[256 * 64];

  const int tid  = threadIdx.x;
  const int lane = tid & 63;
  const int wid  = tid >> 6;
  const int qd   = lane >> 4;
  const int c16  = lane & 15;
  const int p0   = blockIdx.x * 64;
  const floatx4 zero4 = {0.f, 0.f, 0.f, 0.f};

  floatx4 acc[20];
#pragma unroll
  for (int i = 0; i < 20; ++i) acc[i] = zero4;

  for (int kk = 0; kk < 256; kk += 32) {
    {
      const int r = tid >> 2, g = tid & 3;
      const floatx4* s4 = (const floatx4*)(x + (size_t)(p0 + r) * NC + kk + g * 8);
      const floatx4 xa = s4[0], xb = s4[1];
      half8 h;
      h[0] = (f16)xa[0]; h[1] = (f16)xa[1]; h[2] = (f16)xa[2]; h[3] = (f16)xa[3];
      h[4] = (f16)xb[0]; h[5] = (f16)xb[1]; h[6] = (f16)xb[2]; h[7] = (f16)xb[3];
      *(half8*)&xs[r * 32 + g * 8] = h;
    }
#pragma unroll
    for (int i = 0; i < 10; ++i) {
      const int cid = tid + 256 * i;
      const int j = cid >> 3, m = cid & 7;
      *(half4*)&wsT[j * 32 + m * 4] = *(const half4*)&g_WbT[j * 256 + kk + m * 4];
    }
    __syncthreads();
    const half8 a = *(const half8*)&xs[(wid * 16 + c16) * 32 + qd * 8];
#pragma unroll
    for (int nt = 0; nt < 20; ++nt) {
      const half8 bfr = *(const half8*)&wsT[(nt * 16 + c16) * 32 + qd * 8];
      acc[nt] = MFMA_F16(a, bfr, acc[nt]);
    }
    __syncthreads();
  }

#pragma unroll
  for (int nt = 0; nt < 20; ++nt) {
    const int j = nt * 16 + c16;
    const float bias = (j < 32) ? bq[j] : (j < 64) ? bk[j - 32] : bv[j - 64];
#pragma unroll
    for (int r = 0; r < 4; ++r) {
      const int rl = wid * 16 + qd * 4 + r;
      const int p  = p0 + rl;
      const float val = acc[nt][r] + bias;
      if (j < 32) {
        g_Qh[(size_t)p * ND + j] = (f16)val;
      } else if (j < 64) {
        g_Kh[(size_t)p * ND + (j - 32)] = (f16)val;
      } else {
        vt[(j - 64) * 64 + rl] = (f16)val;
      }
    }
  }
  __syncthreads();
  const int b  = p0 >> 12;
  const int n0 = p0 & (NN - 1);
#pragma unroll
  for (int i = 0; i < 16; ++i) {
    const int cid = tid + 256 * i;
    const int c = cid >> 4, m = cid & 15;
    *(half4*)(g_VbT + ((size_t)(b * NC + c)) * NN + n0 + m * 4) =
        *(const half4*)&vt[c * 64 + m * 4];
  }
}

// ---------------------------------------------------------------------------
// Flash attention, 4-way key split. Block = 64 q-rows (4 waves x 16),
// blockIdx.z picks a 1024-key range. Partial (O/l, m, l) -> scratch.
__global__ __launch_bounds__(256) void attn_split(const float* __restrict__ x) {
  __shared__ f16 ks[32 * PAD];       // [key][feat padded]
  __shared__ f16 vsT[256 * PAD];     // [c][key padded]
  __shared__ f16 ps[4 * 16 * PAD];   // [wave][q][key padded]

  const int tid  = threadIdx.x;
  const int lane = tid & 63;
  const int wid  = tid >> 6;
  const int qd   = lane >> 4;
  const int c16  = lane & 15;
  const int b    = blockIdx.y;
  const int s    = blockIdx.z;
  const int q0   = blockIdx.x * 64 + wid * 16;
  const floatx4 zero4 = {0.f, 0.f, 0.f, 0.f};

  const half8 qf = *(const half8*)(g_Qh + ((size_t)(b * NN + q0 + c16)) * ND + qd * 8);

  floatx4 acc[16];
#pragma unroll
  for (int i = 0; i < 16; ++i) acc[i] = zero4;
  float m_i = -1e30f, l_i = 0.f;

  for (int k0 = s * KS; k0 < (s + 1) * KS; k0 += 32) {
    // stage K tile
    if (tid < 128) {
      const int key = tid >> 2, part = tid & 3;
      *(half8*)&ks[key * PAD + part * 8] =
          *(const half8*)(g_Kh + ((size_t)(b * NN + k0 + key)) * ND + part * 8);
    }
    // stage V^T tile
#pragma unroll
    for (int i = 0; i < 4; ++i) {
      const int v = tid + 256 * i;
      const int c = v >> 2, part = v & 3;
      *(half8*)&vsT[c * PAD + part * 8] =
          *(const half8*)(g_VbT + ((size_t)(b * NC + c)) * NN + k0 + part * 8);
    }
    __syncthreads();

    // S^T = K * Q^T
    const half8 a0 = *(const half8*)&ks[c16 * PAD + qd * 8];
    const half8 a1 = *(const half8*)&ks[(16 + c16) * PAD + qd * 8];
    floatx4 st0 = MFMA_F16(a0, qf, zero4);
    floatx4 st1 = MFMA_F16(a1, qf, zero4);

    // online softmax (row q = c16, replicated across quads)
    float tm = fmaxf(fmaxf(fmaxf(st0[0], st0[1]), fmaxf(st0[2], st0[3])),
                     fmaxf(fmaxf(st1[0], st1[1]), fmaxf(st1[2], st1[3])));
    tm = fmaxf(tm, __shfl_xor(tm, 16));
    tm = fmaxf(tm, __shfl_xor(tm, 32));
    const float m_new = fmaxf(m_i, tm);
    const float alpha = __expf(m_i - m_new);

    float p0v[4], p1v[4];
    float ts = 0.f;
#pragma unroll
    for (int r = 0; r < 4; ++r) { p0v[r] = __expf(st0[r] - m_new); ts += p0v[r]; }
#pragma unroll
    for (int r = 0; r < 4; ++r) { p1v[r] = __expf(st1[r] - m_new); ts += p1v[r]; }
    ts += __shfl_xor(ts, 16);
    ts += __shfl_xor(ts, 32);
    l_i = alpha * l_i + ts;
    m_i = m_new;

    // P: C-layout -> LDS -> A-layout
    half4 h0, h1;
#pragma unroll
    for (int r = 0; r < 4; ++r) { h0[r] = (f16)p0v[r]; h1[r] = (f16)p1v[r]; }
    *(half4*)&ps[wid * 16 * PAD + c16 * PAD + qd * 4] = h0;
    *(half4*)&ps[wid * 16 * PAD + c16 * PAD + 16 + qd * 4] = h1;

    // O rescale (skipped once running max stabilizes)
    if (__any(alpha < 1.0f)) {
      float a4[4];
#pragma unroll
      for (int r = 0; r < 4; ++r) a4[r] = __shfl(alpha, qd * 4 + r);
#pragma unroll
      for (int nt = 0; nt < 16; ++nt) {
#pragma unroll
        for (int r = 0; r < 4; ++r) acc[nt][r] *= a4[r];
      }
    }

    // PV
    const half8 pa = *(const half8*)&ps[wid * 16 * PAD + c16 * PAD + qd * 8];
#pragma unroll
    for (int nt = 0; nt < 16; ++nt) {
      const half8 bfr = *(const half8*)&vsT[(nt * 16 + c16) * PAD + qd * 8];
      acc[nt] = MFMA_F16(pa, bfr, acc[nt]);
    }
    __syncthreads();
  }

  // epilogue: store normalized partial O (f16) + m, l
  float linv[4];
#pragma unroll
  for (int r = 0; r < 4; ++r) linv[r] = 1.0f / __shfl(l_i, qd * 4 + r);
  if (qd == 0) {
    const int row = b * NN + q0 + c16;
    g_m[s * PIX + row] = m_i;
    g_l[s * PIX + row] = l_i;
  }
#pragma unroll
  for (int nt = 0; nt < 16; ++nt) {
#pragma unroll
    for (int r = 0; r < 4; ++r) {
      const int qrow = q0 + qd * 4 + r;
      const int c = nt * 16 + c16;
      g_Of[((size_t)(s * PIX + b * NN + qrow)) * NC + c] = (f16)(acc[nt][r] * linv[r]);
    }
  }
}

// ---------------------------------------------------------------------------
// Merge the NS partials: out = sum_s w_s * O_s + x,  w_s = l_s*exp(m_s-M)/den.
// One wave per q-row; each lane handles 4 channels.
__global__ __launch_bounds__(256) void combine(const float* __restrict__ x,
                                               float* __restrict__ out) {
  const int tid  = threadIdx.x;
  const int lane = tid & 63;
  const int wid  = tid >> 6;
  const int row  = blockIdx.x * 4 + wid;  // 0..PIX-1
  const int c    = lane * 4;

  float m[NS], l[NS], M = -1e30f;
#pragma unroll
  for (int s = 0; s < NS; ++s) {
    m[s] = g_m[s * PIX + row];
    l[s] = g_l[s * PIX + row];
    M = fmaxf(M, m[s]);
  }
  float w[NS], den = 0.f;
#pragma unroll
  for (int s = 0; s < NS; ++s) { w[s] = l[s] * __expf(m[s] - M); den += w[s]; }
  const float inv = 1.0f / den;

  float a0 = 0.f, a1 = 0.f, a2 = 0.f, a3 = 0.f;
#pragma unroll
  for (int s = 0; s < NS; ++s) {
    const half4 h = *(const half4*)&g_Of[((size_t)(s * PIX + row)) * NC + c];
    const float ws = w[s] * inv;
    a0 += ws * (float)h[0];
    a1 += ws * (float)h[1];
    a2 += ws * (float)h[2];
    a3 += ws * (float)h[3];
  }
  const floatx4 xv = *(const floatx4*)&x[(size_t)row * NC + c];
  floatx4 o;
  o[0] = a0 + xv[0]; o[1] = a1 + xv[1]; o[2] = a2 + xv[2]; o[3] = a3 + xv[3];
  *(floatx4*)&out[(size_t)row * NC + c] = o;
}

// ---------------------------------------------------------------------------
extern "C" void kernel_launch(void* const* d_in, const int* in_sizes, int n_in,
                              void* d_out, int out_size, void* d_ws, size_t ws_size,
                              hipStream_t stream) {
  (void)in_sizes; (void)n_in; (void)d_ws; (void)ws_size; (void)out_size;
  const float* x  = (const float*)d_in[0];
  const float* wq = (const float*)d_in[1];
  const float* bq = (const float*)d_in[2];
  const float* wk = (const float*)d_in[3];
  const float* bk = (const float*)d_in[4];
  const float* wv = (const float*)d_in[5];
  const float* bv = (const float*)d_in[6];
  float* out = (float*)d_out;

  hipLaunchKernelGGL(prep_weights, dim3(320), dim3(256), 0, stream, wq, wk, wv);
  hipLaunchKernelGGL(proj_qkv, dim3(256), dim3(256), 0, stream, x, bq, bk, bv);
  hipLaunchKernelGGL(attn_split, dim3(64, NB, NS), dim3(256), 0, stream, x);
  hipLaunchKernelGGL(combine, dim3(PIX / 4), dim3(256), 0, stream, x, out);
}

// Round 5
// 169.582 us; speedup vs baseline: 1.8337x; 1.3681x over previous
//
#include <hip/hip_runtime.h>
#include <stdint.h>

typedef _Float16 f16;
typedef f16 half8 __attribute__((ext_vector_type(8)));
typedef f16 half4 __attribute__((ext_vector_type(4)));
typedef float floatx4 __attribute__((ext_vector_type(4)));

#define MFMA_F16(A, B, Cc) __builtin_amdgcn_mfma_f32_16x16x32_f16((A), (B), (Cc), 0, 0, 0)

// Problem constants: B=4, H=W=64 -> N=4096, C=256, d=32
static constexpr int NB  = 4;
static constexpr int NN  = 4096;
static constexpr int NC  = 256;
static constexpr int ND  = 32;
static constexpr int PIX = NB * NN;  // 16384
static constexpr int NS  = 4;        // key splits
static constexpr int KS  = NN / NS;  // 1024 keys per split

// LDS row strides. MUST keep rows 16B-aligned: *(half8*) casts carry align-16
// in IR -> ds_*_b128; a 4B-aligned row (e.g. stride 38 halfs) is UB (round-4
// NaN). 40 halfs = 80 B = 16*5 (dword stride 20 -> 2-way banks, free);
// 72 halfs = 144 B = 16*9 (dword stride 36 -> 2-way).
static constexpr int PADK = 40;  // ks / vsT rows
static constexpr int PADP = 72;  // ps rows (64 keys + pad)

// Device-global scratch. Fully rewritten every launch.
__device__ f16 g_WbT[320 * 256];              // [j][k]
__device__ f16 g_Qh[(size_t)PIX * ND];        // [row][32], pre-scaled by log2(e)
__device__ f16 g_Kh[(size_t)PIX * ND];        // [row][32]
__device__ f16 g_VbT[(size_t)NB * NC * NN];   // [b][c][n]
__device__ f16 g_Of[(size_t)NS * PIX * NC];   // per-split normalized O
__device__ float g_m[NS * PIX];               // per-split max (log2 domain)
__device__ float g_l[NS * PIX];               // per-split denom

// ---------------------------------------------------------------------------
__global__ __launch_bounds__(256) void prep_weights(const float* __restrict__ wq,
                                                    const float* __restrict__ wk,
                                                    const float* __restrict__ wv) {
  const int tid = blockIdx.x * 256 + threadIdx.x;
  if (tid >= 320 * 256) return;
  const int j = tid >> 8;
  const int k = tid & 255;
  float v;
  if (j < 32)      v = wq[k * 32 + j];
  else if (j < 64) v = wk[k * 32 + (j - 32)];
  else             v = wv[k * 256 + (j - 64)];
  g_WbT[j * 256 + k] = (f16)v;
}

// ---------------------------------------------------------------------------
// QKV projection. Q pre-scaled by log2(e) so attention runs in exp2 domain.
__global__ __launch_bounds__(256) void proj_qkv(const float* __restrict__ x,
                                                const float* __restrict__ bq,
                                                const float* __restrict__ bk,
                                                const float* __restrict__ bv) {
  __shared__ f16 xs[64 * 32];
  __shared__ f16 wsT[320 * 32];
  __shared__ f16 vt[256 * 64];

  const int tid  = threadIdx.x;
  const int lane = tid & 63;
  const int wid  = tid >> 6;
  const int qd   = lane >> 4;
  const int c16  = lane & 15;
  const int p0   = blockIdx.x * 64;
  const floatx4 zero4 = {0.f, 0.f, 0.f, 0.f};

  floatx4 acc[20];
#pragma unroll
  for (int i = 0; i < 20; ++i) acc[i] = zero4;

  for (int kk = 0; kk < 256; kk += 32) {
    {
      const int r = tid >> 2, g = tid & 3;
      const floatx4* s4 = (const floatx4*)(x + (size_t)(p0 + r) * NC + kk + g * 8);
      const floatx4 xa = s4[0], xb = s4[1];
      half8 h;
      h[0] = (f16)xa[0]; h[1] = (f16)xa[1]; h[2] = (f16)xa[2]; h[3] = (f16)xa[3];
      h[4] = (f16)xb[0]; h[5] = (f16)xb[1]; h[6] = (f16)xb[2]; h[7] = (f16)xb[3];
      *(half8*)&xs[r * 32 + g * 8] = h;
    }
#pragma unroll
    for (int i = 0; i < 10; ++i) {
      const int cid = tid + 256 * i;
      const int j = cid >> 3, m = cid & 7;
      *(half4*)&wsT[j * 32 + m * 4] = *(const half4*)&g_WbT[j * 256 + kk + m * 4];
    }
    __syncthreads();
    const half8 a = *(const half8*)&xs[(wid * 16 + c16) * 32 + qd * 8];
#pragma unroll
    for (int nt = 0; nt < 20; ++nt) {
      const half8 bfr = *(const half8*)&wsT[(nt * 16 + c16) * 32 + qd * 8];
      acc[nt] = MFMA_F16(a, bfr, acc[nt]);
    }
    __syncthreads();
  }

#pragma unroll
  for (int nt = 0; nt < 20; ++nt) {
    const int j = nt * 16 + c16;
    const float bias = (j < 32) ? bq[j] : (j < 64) ? bk[j - 32] : bv[j - 64];
#pragma unroll
    for (int r = 0; r < 4; ++r) {
      const int rl = wid * 16 + qd * 4 + r;
      const int p  = p0 + rl;
      const float val = acc[nt][r] + bias;
      if (j < 32) {
        g_Qh[(size_t)p * ND + j] = (f16)(val * 1.44269504f);  // log2(e)
      } else if (j < 64) {
        g_Kh[(size_t)p * ND + (j - 32)] = (f16)val;
      } else {
        vt[(j - 64) * 64 + rl] = (f16)val;
      }
    }
  }
  __syncthreads();
  const int b  = p0 >> 12;
  const int n0 = p0 & (NN - 1);
#pragma unroll
  for (int i = 0; i < 16; ++i) {
    const int cid = tid + 256 * i;
    const int c = cid >> 4, m = cid & 15;
    *(half4*)(g_VbT + ((size_t)(b * NC + c)) * NN + n0 + m * 4) =
        *(const half4*)&vt[c * 64 + m * 4];
  }
}

// ---------------------------------------------------------------------------
// Flash attention: block = 128 q (4 waves x 32 q), K-tile = 64 keys,
// blockIdx.z = 1024-key split. Lazy max (overshoot +5, log2 domain).
__global__ __launch_bounds__(256, 2) void attn_split(void) {
  __shared__ f16 ks[64 * PADK];          //  5120 B  [key][d]
  __shared__ f16 vsT[2][256 * PADK];     // 40960 B  [keyhalf][c][key]
  __shared__ f16 ps[4][2][16 * PADP];    // 18432 B  [wave][qgroup][q][64 keys]

  const int tid  = threadIdx.x;
  const int lane = tid & 63;
  const int wid  = tid >> 6;
  const int qd   = lane >> 4;
  const int c16  = lane & 15;
  const int b    = blockIdx.y;
  const int s    = blockIdx.z;
  const int q0   = blockIdx.x * 128 + wid * 32;
  const floatx4 zero4 = {0.f, 0.f, 0.f, 0.f};

  half8 qf[2];
#pragma unroll
  for (int g = 0; g < 2; ++g)
    qf[g] = *(const half8*)(g_Qh + ((size_t)(b * NN + q0 + g * 16 + c16)) * ND + qd * 8);

  floatx4 acc[2][16];
#pragma unroll
  for (int g = 0; g < 2; ++g)
#pragma unroll
    for (int i = 0; i < 16; ++i) acc[g][i] = zero4;
  float m_i[2] = {-1e30f, -1e30f};
  float l_p[2] = {0.f, 0.f};

  for (int k0 = s * KS; k0 < (s + 1) * KS; k0 += 64) {
    // ---- stage K tile: 64 keys x 32 d ----
    {
      const int row = tid >> 2, part = tid & 3;
      *(half8*)&ks[row * PADK + part * 8] =
          *(const half8*)(g_Kh + ((size_t)(b * NN + k0 + row)) * ND + part * 8);
    }
    // ---- stage V^T tile: 256 c x 64 keys (two 32-key halves) ----
#pragma unroll
    for (int i = 0; i < 8; ++i) {
      const int id = tid + 256 * i;
      const int c = id >> 3, p = id & 7;
      *(half8*)&vsT[p >> 2][c * PADK + (p & 3) * 8] =
          *(const half8*)(g_VbT + ((size_t)(b * NC + c)) * NN + k0 + p * 8);
    }
    __syncthreads();

    // ---- S^T = K * Q^T : 8 MFMAs ----
    half8 ka[4];
#pragma unroll
    for (int a = 0; a < 4; ++a)
      ka[a] = *(const half8*)&ks[(a * 16 + c16) * PADK + qd * 8];
    floatx4 st[2][4];
#pragma unroll
    for (int g = 0; g < 2; ++g)
#pragma unroll
      for (int a = 0; a < 4; ++a) st[g][a] = MFMA_F16(ka[a], qf[g], zero4);

    // ---- lazy max ----
    float tm[2];
#pragma unroll
    for (int g = 0; g < 2; ++g) {
      float t0 = fmaxf(fmaxf(st[g][0][0], st[g][0][1]), fmaxf(st[g][0][2], st[g][0][3]));
      float t1 = fmaxf(fmaxf(st[g][1][0], st[g][1][1]), fmaxf(st[g][1][2], st[g][1][3]));
      float t2 = fmaxf(fmaxf(st[g][2][0], st[g][2][1]), fmaxf(st[g][2][2], st[g][2][3]));
      float t3 = fmaxf(fmaxf(st[g][3][0], st[g][3][1]), fmaxf(st[g][3][2], st[g][3][3]));
      tm[g] = fmaxf(fmaxf(t0, t1), fmaxf(t2, t3));
    }
    if (__any(tm[0] > m_i[0] || tm[1] > m_i[1])) {
#pragma unroll
      for (int g = 0; g < 2; ++g) {
        float tr = tm[g];
        tr = fmaxf(tr, __shfl_xor(tr, 16));
        tr = fmaxf(tr, __shfl_xor(tr, 32));
        const float m_new = (tr > m_i[g]) ? tr + 5.0f : m_i[g];
        const float alpha = exp2f(m_i[g] - m_new);  // ==1 when unchanged
        m_i[g] = m_new;
        l_p[g] *= alpha;
        float a4[4];
#pragma unroll
        for (int r = 0; r < 4; ++r) a4[r] = __shfl(alpha, qd * 4 + r);
#pragma unroll
        for (int ct = 0; ct < 16; ++ct)
#pragma unroll
          for (int r = 0; r < 4; ++r) acc[g][ct][r] *= a4[r];
      }
    }

    // ---- P = exp2(s - m), per-lane partial l, pack to LDS ----
#pragma unroll
    for (int g = 0; g < 2; ++g) {
      float ts = 0.f;
#pragma unroll
      for (int a = 0; a < 4; ++a) {
        half4 h;
#pragma unroll
        for (int r = 0; r < 4; ++r) {
          const float p = exp2f(st[g][a][r] - m_i[g]);
          ts += p;
          h[r] = (f16)p;
        }
        *(half4*)&ps[wid][g][c16 * PADP + a * 16 + qd * 4] = h;
      }
      l_p[g] += ts;
    }
    // pin IR ordering of the ps store->load round-trip (same-wave DS is
    // in-order in HW; this is a zero-cost compiler barrier)
    asm volatile("" ::: "memory");

    // ---- PV: O += P * V, 64 MFMAs; V frags shared across both q-groups ----
    half8 pa[2][2];
#pragma unroll
    for (int g = 0; g < 2; ++g)
#pragma unroll
      for (int kh = 0; kh < 2; ++kh)
        pa[g][kh] = *(const half8*)&ps[wid][g][c16 * PADP + kh * 32 + qd * 8];
#pragma unroll
    for (int ct = 0; ct < 16; ++ct) {
#pragma unroll
      for (int kh = 0; kh < 2; ++kh) {
        const half8 bfr = *(const half8*)&vsT[kh][(ct * 16 + c16) * PADK + qd * 8];
        acc[0][ct] = MFMA_F16(pa[0][kh], bfr, acc[0][ct]);
        acc[1][ct] = MFMA_F16(pa[1][kh], bfr, acc[1][ct]);
      }
    }
    __syncthreads();
  }

  // ---- epilogue ----
#pragma unroll
  for (int g = 0; g < 2; ++g) {
    float l = l_p[g];
    l += __shfl_xor(l, 16);
    l += __shfl_xor(l, 32);
    if (qd == 0) {
      const int row = b * NN + q0 + g * 16 + c16;
      g_m[s * PIX + row] = m_i[g];
      g_l[s * PIX + row] = l;
    }
    float linv[4];
#pragma unroll
    for (int r = 0; r < 4; ++r) linv[r] = 1.0f / __shfl(l, qd * 4 + r);
#pragma unroll
    for (int ct = 0; ct < 16; ++ct)
#pragma unroll
      for (int r = 0; r < 4; ++r) {
        const int qrow = q0 + g * 16 + qd * 4 + r;
        const int c = ct * 16 + c16;
        g_Of[((size_t)(s * PIX + b * NN + qrow)) * NC + c] = (f16)(acc[g][ct][r] * linv[r]);
      }
  }
}

// ---------------------------------------------------------------------------
// Merge NS partials (log2 domain): w_s = l_s * 2^(m_s - M) / den.
__global__ __launch_bounds__(256) void combine(const float* __restrict__ x,
                                               float* __restrict__ out) {
  const int tid  = threadIdx.x;
  const int lane = tid & 63;
  const int wid  = tid >> 6;
  const int row  = blockIdx.x * 4 + wid;
  const int c    = lane * 4;

  float m[NS], l[NS], M = -1e30f;
#pragma unroll
  for (int s = 0; s < NS; ++s) {
    m[s] = g_m[s * PIX + row];
    l[s] = g_l[s * PIX + row];
    M = fmaxf(M, m[s]);
  }
  float w[NS], den = 0.f;
#pragma unroll
  for (int s = 0; s < NS; ++s) { w[s] = l[s] * exp2f(m[s] - M); den += w[s]; }
  const float inv = 1.0f / den;

  float a0 = 0.f, a1 = 0.f, a2 = 0.f, a3 = 0.f;
#pragma unroll
  for (int s = 0; s < NS; ++s) {
    const half4 h = *(const half4*)&g_Of[((size_t)(s * PIX + row)) * NC + c];
    const float ws = w[s] * inv;
    a0 += ws * (float)h[0];
    a1 += ws * (float)h[1];
    a2 += ws * (float)h[2];
    a3 += ws * (float)h[3];
  }
  const floatx4 xv = *(const floatx4*)&x[(size_t)row * NC + c];
  floatx4 o;
  o[0] = a0 + xv[0]; o[1] = a1 + xv[1]; o[2] = a2 + xv[2]; o[3] = a3 + xv[3];
  *(floatx4*)&out[(size_t)row * NC + c] = o;
}

// ---------------------------------------------------------------------------
extern "C" void kernel_launch(void* const* d_in, const int* in_sizes, int n_in,
                              void* d_out, int out_size, void* d_ws, size_t ws_size,
                              hipStream_t stream) {
  (void)in_sizes; (void)n_in; (void)d_ws; (void)ws_size; (void)out_size;
  const float* x  = (const float*)d_in[0];
  const float* wq = (const float*)d_in[1];
  const float* bq = (const float*)d_in[2];
  const float* wk = (const float*)d_in[3];
  const float* bk = (const float*)d_in[4];
  const float* wv = (const float*)d_in[5];
  const float* bv = (const float*)d_in[6];
  float* out = (float*)d_out;

  hipLaunchKernelGGL(prep_weights, dim3(320), dim3(256), 0, stream, wq, wk, wv);
  hipLaunchKernelGGL(proj_qkv, dim3(256), dim3(256), 0, stream, x, bq, bk, bv);
  hipLaunchKernelGGL(attn_split, dim3(NN / 128, NB, NS), dim3(256), 0, stream);
  hipLaunchKernelGGL(combine, dim3(PIX / 4), dim3(256), 0, stream, x, out);
}

// Round 6
// 164.852 us; speedup vs baseline: 1.8863x; 1.0287x over previous
//
#include <hip/hip_runtime.h>
#include <stdint.h>

typedef _Float16 f16;
typedef f16 half8 __attribute__((ext_vector_type(8)));
typedef f16 half4 __attribute__((ext_vector_type(4)));
typedef float floatx4 __attribute__((ext_vector_type(4)));

#define MFMA_F16(A, B, Cc) __builtin_amdgcn_mfma_f32_16x16x32_f16((A), (B), (Cc), 0, 0, 0)

// Problem constants: B=4, H=W=64 -> N=4096, C=256, d=32
static constexpr int NB  = 4;
static constexpr int NN  = 4096;
static constexpr int NC  = 256;
static constexpr int ND  = 32;
static constexpr int PIX = NB * NN;  // 16384
static constexpr int NS  = 4;        // key splits
static constexpr int KS  = NN / NS;  // 1024 keys per split

// Device-global scratch. Fully rewritten every launch.
__device__ f16 g_WbT[320 * 256];              // [j][k]
__device__ f16 g_Qh[(size_t)PIX * ND];        // [row][32], pre-scaled by log2(e)
__device__ f16 g_Kh[(size_t)PIX * ND];        // [row][32]
__device__ f16 g_VbT[(size_t)NB * NC * NN];   // [b][c][n]
__device__ f16 g_Of[(size_t)NS * PIX * NC];   // per-split normalized O
__device__ float g_m[NS * PIX];               // per-split max (log2 domain)
__device__ float g_l[NS * PIX];               // per-split denom

__device__ inline void gl2lds16(const f16* g, f16* l) {
  __builtin_amdgcn_global_load_lds(
      (const __attribute__((address_space(1))) void*)g,
      (__attribute__((address_space(3))) void*)l, 16, 0, 0);
}

// ---------------------------------------------------------------------------
__global__ __launch_bounds__(256) void prep_weights(const float* __restrict__ wq,
                                                    const float* __restrict__ wk,
                                                    const float* __restrict__ wv) {
  const int tid = blockIdx.x * 256 + threadIdx.x;
  if (tid >= 320 * 256) return;
  const int j = tid >> 8;
  const int k = tid & 255;
  float v;
  if (j < 32)      v = wq[k * 32 + j];
  else if (j < 64) v = wk[k * 32 + (j - 32)];
  else             v = wv[k * 256 + (j - 64)];
  g_WbT[j * 256 + k] = (f16)v;
}

// ---------------------------------------------------------------------------
// QKV projection (unchanged from round 5). Q pre-scaled by log2(e).
__global__ __launch_bounds__(256) void proj_qkv(const float* __restrict__ x,
                                                const float* __restrict__ bq,
                                                const float* __restrict__ bk,
                                                const float* __restrict__ bv) {
  __shared__ f16 xs[64 * 32];
  __shared__ f16 wsT[320 * 32];
  __shared__ f16 vt[256 * 64];

  const int tid  = threadIdx.x;
  const int lane = tid & 63;
  const int wid  = tid >> 6;
  const int qd   = lane >> 4;
  const int c16  = lane & 15;
  const int p0   = blockIdx.x * 64;
  const floatx4 zero4 = {0.f, 0.f, 0.f, 0.f};

  floatx4 acc[20];
#pragma unroll
  for (int i = 0; i < 20; ++i) acc[i] = zero4;

  for (int kk = 0; kk < 256; kk += 32) {
    {
      const int r = tid >> 2, g = tid & 3;
      const floatx4* s4 = (const floatx4*)(x + (size_t)(p0 + r) * NC + kk + g * 8);
      const floatx4 xa = s4[0], xb = s4[1];
      half8 h;
      h[0] = (f16)xa[0]; h[1] = (f16)xa[1]; h[2] = (f16)xa[2]; h[3] = (f16)xa[3];
      h[4] = (f16)xb[0]; h[5] = (f16)xb[1]; h[6] = (f16)xb[2]; h[7] = (f16)xb[3];
      *(half8*)&xs[r * 32 + g * 8] = h;
    }
#pragma unroll
    for (int i = 0; i < 10; ++i) {
      const int cid = tid + 256 * i;
      const int j = cid >> 3, m = cid & 7;
      *(half4*)&wsT[j * 32 + m * 4] = *(const half4*)&g_WbT[j * 256 + kk + m * 4];
    }
    __syncthreads();
    const half8 a = *(const half8*)&xs[(wid * 16 + c16) * 32 + qd * 8];
#pragma unroll
    for (int nt = 0; nt < 20; ++nt) {
      const half8 bfr = *(const half8*)&wsT[(nt * 16 + c16) * 32 + qd * 8];
      acc[nt] = MFMA_F16(a, bfr, acc[nt]);
    }
    __syncthreads();
  }

#pragma unroll
  for (int nt = 0; nt < 20; ++nt) {
    const int j = nt * 16 + c16;
    const float bias = (j < 32) ? bq[j] : (j < 64) ? bk[j - 32] : bv[j - 64];
#pragma unroll
    for (int r = 0; r < 4; ++r) {
      const int rl = wid * 16 + qd * 4 + r;
      const int p  = p0 + rl;
      const float val = acc[nt][r] + bias;
      if (j < 32) {
        g_Qh[(size_t)p * ND + j] = (f16)(val * 1.44269504f);  // log2(e)
      } else if (j < 64) {
        g_Kh[(size_t)p * ND + (j - 32)] = (f16)val;
      } else {
        vt[(j - 64) * 64 + rl] = (f16)val;
      }
    }
  }
  __syncthreads();
  const int b  = p0 >> 12;
  const int n0 = p0 & (NN - 1);
#pragma unroll
  for (int i = 0; i < 16; ++i) {
    const int cid = tid + 256 * i;
    const int c = cid >> 4, m = cid & 15;
    *(half4*)(g_VbT + ((size_t)(b * NC + c)) * NN + n0 + m * 4) =
        *(const half4*)&vt[c * 64 + m * 4];
  }
}

// ---------------------------------------------------------------------------
// Flash attention: block = 128 q (4 waves x 32 q), K-tile = 64 keys,
// blockIdx.z = 1024-key split. K direct from global (reg double-buffer);
// V async global_load_lds into XOR-swizzled vsT; P via XOR-swizzled ps.
// Physical 16B chunk = logical chunk ^ (row & 7)  -> conflict-minimal LDS.
__global__ __launch_bounds__(256, 2) void attn_split(void) {
  __shared__ f16 vsT[256 * 64];        // 32 KB  [c][64 keys], chunk-swizzled
  __shared__ f16 ps[4][2][16 * 64];    // 16 KB  [wave][qgrp][q][64 keys], swizzled

  const int tid  = threadIdx.x;
  const int lane = tid & 63;
  const int wid  = tid >> 6;
  const int qd   = lane >> 4;
  const int c16  = lane & 15;
  const int b    = blockIdx.y;
  const int s    = blockIdx.z;
  const int q0   = blockIdx.x * 128 + wid * 32;
  const int sx7  = c16 & 7;  // row&7 for this lane's reads
  const floatx4 zero4 = {0.f, 0.f, 0.f, 0.f};

  // Per-lane V staging source: wave wid stages c rows [wid*64, wid*64+64).
  // LDS dest of gl_lds is wave-uniform base + lane*16 (lane-linear), so the
  // XOR swizzle is applied to the GLOBAL source chunk instead.
  const int vrow = wid * 64 + (lane >> 3);
  const int vchk = (lane & 7) ^ ((lane >> 3) & 7);
  const f16* vlane = g_VbT + ((size_t)(b * NC + vrow)) * NN + vchk * 8;
  f16* vdst = &vsT[(size_t)wid * 4096 + (size_t)0];  // + i*512 per instr

  // Q fragments (B-operand)
  half8 qf[2];
#pragma unroll
  for (int g = 0; g < 2; ++g)
    qf[g] = *(const half8*)(g_Qh + ((size_t)(b * NN + q0 + g * 16 + c16)) * ND + qd * 8);

  floatx4 acc[2][16];
#pragma unroll
  for (int g = 0; g < 2; ++g)
#pragma unroll
    for (int i = 0; i < 16; ++i) acc[g][i] = zero4;
  float m_i[2] = {-1e30f, -1e30f};
  float l_p[2] = {0.f, 0.f};

  const int kbeg = s * KS, kend = (s + 1) * KS;

  // prologue: V(kbeg) async -> LDS; K(kbeg) -> regs
#pragma unroll
  for (int i = 0; i < 8; ++i)
    gl2lds16(vlane + kbeg + i * 8 * NN, vdst + i * 512);
  half8 kreg[4];
#pragma unroll
  for (int a = 0; a < 4; ++a)
    kreg[a] = *(const half8*)(g_Kh + ((size_t)(b * NN + kbeg + a * 16 + c16)) * ND + qd * 8);

  for (int k0 = kbeg; k0 < kend; k0 += 64) {
    // ---- S^T = K * Q^T from registers (no LDS dependency) ----
    floatx4 st[2][4];
#pragma unroll
    for (int g = 0; g < 2; ++g)
#pragma unroll
      for (int a = 0; a < 4; ++a) st[g][a] = MFMA_F16(kreg[a], qf[g], zero4);

    // ---- lazy max (overshoot +5, log2 domain) ----
    float tm[2];
#pragma unroll
    for (int g = 0; g < 2; ++g) {
      float t0 = fmaxf(fmaxf(st[g][0][0], st[g][0][1]), fmaxf(st[g][0][2], st[g][0][3]));
      float t1 = fmaxf(fmaxf(st[g][1][0], st[g][1][1]), fmaxf(st[g][1][2], st[g][1][3]));
      float t2 = fmaxf(fmaxf(st[g][2][0], st[g][2][1]), fmaxf(st[g][2][2], st[g][2][3]));
      float t3 = fmaxf(fmaxf(st[g][3][0], st[g][3][1]), fmaxf(st[g][3][2], st[g][3][3]));
      tm[g] = fmaxf(fmaxf(t0, t1), fmaxf(t2, t3));
    }
    if (__any(tm[0] > m_i[0] || tm[1] > m_i[1])) {
#pragma unroll
      for (int g = 0; g < 2; ++g) {
        float tr = tm[g];
        tr = fmaxf(tr, __shfl_xor(tr, 16));
        tr = fmaxf(tr, __shfl_xor(tr, 32));
        const float m_new = (tr > m_i[g]) ? tr + 5.0f : m_i[g];
        const float alpha = exp2f(m_i[g] - m_new);
        m_i[g] = m_new;
        l_p[g] *= alpha;
        float a4[4];
#pragma unroll
        for (int r = 0; r < 4; ++r) a4[r] = __shfl(alpha, qd * 4 + r);
#pragma unroll
        for (int ct = 0; ct < 16; ++ct)
#pragma unroll
          for (int r = 0; r < 4; ++r) acc[g][ct][r] *= a4[r];
      }
    }

    // ---- P = exp2(s - m), per-lane partial l, swizzled ps write ----
    // key = a*16 + qd*4  -> chunk a*2+(qd>>1), sub-offset (qd&1)*4
#pragma unroll
    for (int g = 0; g < 2; ++g) {
      float ts = 0.f;
#pragma unroll
      for (int a = 0; a < 4; ++a) {
        half4 h;
#pragma unroll
        for (int r = 0; r < 4; ++r) {
          const float p = exp2f(st[g][a][r] - m_i[g]);
          ts += p;
          h[r] = (f16)p;
        }
        const int pc = ((a * 2 + (qd >> 1)) ^ sx7) * 8 + (qd & 1) * 4;
        *(half4*)&ps[wid][g][c16 * 64 + pc] = h;
      }
      l_p[g] += ts;
    }

    __syncthreads();  // [A] compiler drains vmcnt -> vsT(k0) landed everywhere

    // ---- prefetch K(next) into regs (latency covered by PV MFMAs) ----
    const int k0n = (k0 + 64 < kend) ? (k0 + 64) : kbeg;
    half8 knew[4];
#pragma unroll
    for (int a = 0; a < 4; ++a)
      knew[a] = *(const half8*)(g_Kh + ((size_t)(b * NN + k0n + a * 16 + c16)) * ND + qd * 8);

    // ---- PV: O += P * V, 64 MFMAs; swizzled reads ----
    half8 pa[2][2];
#pragma unroll
    for (int g = 0; g < 2; ++g)
#pragma unroll
      for (int kh = 0; kh < 2; ++kh)
        pa[g][kh] = *(const half8*)&ps[wid][g][c16 * 64 + ((kh * 4 + qd) ^ sx7) * 8];
#pragma unroll
    for (int ct = 0; ct < 16; ++ct) {
#pragma unroll
      for (int kh = 0; kh < 2; ++kh) {
        const half8 bfr =
            *(const half8*)&vsT[(ct * 16 + c16) * 64 + ((kh * 4 + qd) ^ sx7) * 8];
        acc[0][ct] = MFMA_F16(pa[0][kh], bfr, acc[0][ct]);
        acc[1][ct] = MFMA_F16(pa[1][kh], bfr, acc[1][ct]);
      }
    }
    __syncthreads();  // [B] all waves done reading vsT(k0)

    // ---- issue async V(k+1) -> LDS (in flight until next [A]) ----
    if (k0 + 64 < kend) {
#pragma unroll
      for (int i = 0; i < 8; ++i)
        gl2lds16(vlane + (k0 + 64) + i * 8 * NN, vdst + i * 512);
    }
#pragma unroll
    for (int a = 0; a < 4; ++a) kreg[a] = knew[a];
  }

  // ---- epilogue ----
#pragma unroll
  for (int g = 0; g < 2; ++g) {
    float l = l_p[g];
    l += __shfl_xor(l, 16);
    l += __shfl_xor(l, 32);
    if (qd == 0) {
      const int row = b * NN + q0 + g * 16 + c16;
      g_m[s * PIX + row] = m_i[g];
      g_l[s * PIX + row] = l;
    }
    float linv[4];
#pragma unroll
    for (int r = 0; r < 4; ++r) linv[r] = 1.0f / __shfl(l, qd * 4 + r);
#pragma unroll
    for (int ct = 0; ct < 16; ++ct)
#pragma unroll
      for (int r = 0; r < 4; ++r) {
        const int qrow = q0 + g * 16 + qd * 4 + r;
        const int c = ct * 16 + c16;
        g_Of[((size_t)(s * PIX + b * NN + qrow)) * NC + c] = (f16)(acc[g][ct][r] * linv[r]);
      }
  }
}

// ---------------------------------------------------------------------------
// Merge NS partials (log2 domain): w_s = l_s * 2^(m_s - M) / den.
__global__ __launch_bounds__(256) void combine(const float* __restrict__ x,
                                               float* __restrict__ out) {
  const int tid  = threadIdx.x;
  const int lane = tid & 63;
  const int wid  = tid >> 6;
  const int row  = blockIdx.x * 4 + wid;
  const int c    = lane * 4;

  float m[NS], l[NS], M = -1e30f;
#pragma unroll
  for (int s = 0; s < NS; ++s) {
    m[s] = g_m[s * PIX + row];
    l[s] = g_l[s * PIX + row];
    M = fmaxf(M, m[s]);
  }
  float w[NS], den = 0.f;
#pragma unroll
  for (int s = 0; s < NS; ++s) { w[s] = l[s] * exp2f(m[s] - M); den += w[s]; }
  const float inv = 1.0f / den;

  float a0 = 0.f, a1 = 0.f, a2 = 0.f, a3 = 0.f;
#pragma unroll
  for (int s = 0; s < NS; ++s) {
    const half4 h = *(const half4*)&g_Of[((size_t)(s * PIX + row)) * NC + c];
    const float ws = w[s] * inv;
    a0 += ws * (float)h[0];
    a1 += ws * (float)h[1];
    a2 += ws * (float)h[2];
    a3 += ws * (float)h[3];
  }
  const floatx4 xv = *(const floatx4*)&x[(size_t)row * NC + c];
  floatx4 o;
  o[0] = a0 + xv[0]; o[1] = a1 + xv[1]; o[2] = a2 + xv[2]; o[3] = a3 + xv[3];
  *(floatx4*)&out[(size_t)row * NC + c] = o;
}

// ---------------------------------------------------------------------------
extern "C" void kernel_launch(void* const* d_in, const int* in_sizes, int n_in,
                              void* d_out, int out_size, void* d_ws, size_t ws_size,
                              hipStream_t stream) {
  (void)in_sizes; (void)n_in; (void)d_ws; (void)ws_size; (void)out_size;
  const float* x  = (const float*)d_in[0];
  const float* wq = (const float*)d_in[1];
  const float* bq = (const float*)d_in[2];
  const float* wk = (const float*)d_in[3];
  const float* bk = (const float*)d_in[4];
  const float* wv = (const float*)d_in[5];
  const float* bv = (const float*)d_in[6];
  float* out = (float*)d_out;

  hipLaunchKernelGGL(prep_weights, dim3(320), dim3(256), 0, stream, wq, wk, wv);
  hipLaunchKernelGGL(proj_qkv, dim3(256), dim3(256), 0, stream, x, bq, bk, bv);
  hipLaunchKernelGGL(attn_split, dim3(NN / 128, NB, NS), dim3(256), 0, stream);
  hipLaunchKernelGGL(combine, dim3(PIX / 4), dim3(256), 0, stream, x, out);
}